// Round 4
// baseline (1445.866 us; speedup 1.0000x reference)
//
#include <hip/hip_runtime.h>
#include <math.h>

// SeaLiceGLKAN — fp32 in/out. lane=node register-GEMM for dense parts,
// lane=H for edge gathers. z_t layout: [row][node], rows 0..63 = h (transposed),
// rows 64..127 = p-accumulator (khop sum, then final p).

constexpr int cB = 2, cT = 4, cN = 10000, cF = 16, cH = 64, cE = 160000, cNB = 8, cK = 3;
constexpr int cBN = cB * cN;    // 20000
constexpr int cBNH = cBN * cH;  // 1,280,000
constexpr int NBLK = (cBN + 63) / 64;  // 313 blocks of 64 nodes

typedef const float* fp;

__device__ __forceinline__ float wmax(float v) {
#pragma unroll
  for (int o = 1; o < 64; o <<= 1) v = fmaxf(v, __shfl_xor(v, o, 64));
  return v;
}

// ---------------- CSR build ----------------
__global__ void k_zero_i32(int* p, int n) {
  int i = blockIdx.x * 256 + threadIdx.x;
  if (i < n) p[i] = 0;
}

__global__ void k_count(const int* dst, int* counts) {
  int e = blockIdx.x * 256 + threadIdx.x;
  if (e < cE) atomicAdd(&counts[dst[e]], 1);
}

__global__ void k_scan(const int* counts, int* row_ptr, int* cursor) {
  __shared__ int part[1024];
  int t = threadIdx.x;
  const int CH = (cN + 1023) / 1024;  // 10
  int s = 0;
  for (int i = 0; i < CH; i++) {
    int idx = t * CH + i;
    if (idx < cN) s += counts[idx];
  }
  part[t] = s;
  __syncthreads();
  for (int off = 1; off < 1024; off <<= 1) {
    int v = (t >= off) ? part[t - off] : 0;
    __syncthreads();
    part[t] += v;
    __syncthreads();
  }
  int excl = (t == 0) ? 0 : part[t - 1];
  for (int i = 0; i < CH; i++) {
    int idx = t * CH + i;
    if (idx < cN) {
      row_ptr[idx] = excl;
      cursor[idx] = excl;
      excl += counts[idx];
    }
  }
  if (t == 1023) row_ptr[cN] = part[1023];
}

__global__ void k_scatter(const int* src, const int* dst, fp ea, fp w1, fp b1, fp w2, fp b2,
                          int* cursor, int* esrc, float* gcsr) {
  int e = blockIdx.x * 256 + threadIdx.x;
  if (e >= cE) return;
  float a0 = ea[e * 4 + 0], a1 = ea[e * 4 + 1], a2 = ea[e * 4 + 2], a3 = ea[e * 4 + 3];
  float acc = b2[0];
#pragma unroll
  for (int j = 0; j < 16; j++) {
    float tv = b1[j] + a0 * w1[j] + a1 * w1[16 + j] + a2 * w1[32 + j] + a3 * w1[48 + j];
    acc += tanhf(tv) * w2[j];
  }
  float g = 1.f / (1.f + expf(-acc));
  int p = atomicAdd(&cursor[dst[e]], 1);
  esrc[p] = src[e];
  gcsr[p] = g;
}

__global__ void k_init(float* h, float* z_t, fp h0) {
  int i = blockIdx.x * 256 + threadIdx.x;
  if (i < cBNH) {
    h[i] = h0[i & 63];
    z_t[i] = h0[i / cBN];  // rows 0..63 of z_t = h transposed
  }
}

// ---------------- hop matvec: lane=node, 4 waves split 64 cols ----------------
__global__ __launch_bounds__(256) void k_hop_mat_t(const float* vin_t, fp Wh, fp avs, fp avd,
                                                   float* hw, float* ssrc, float* sdst) {
  __shared__ float tile[64 * 65];
  __shared__ float red1[4][64], red2[4][64];
  int w = threadIdx.x >> 6, lane = threadIdx.x & 63;
  int base = blockIdx.x * 64, node = base + lane;
  int nd = node < cBN ? node : cBN - 1;
  int c0 = __builtin_amdgcn_readfirstlane(w * 16);  // wave-uniform column offset
  float acc[16];
#pragma unroll
  for (int c = 0; c < 16; c++) acc[c] = 0.f;
  for (int i = 0; i < 64; i++) {
    float cv = vin_t[(size_t)i * cBN + nd];
#pragma unroll
    for (int c = 0; c < 16; c++) acc[c] += cv * Wh[i * 64 + c0 + c];
  }
  float r1 = 0.f, r2 = 0.f;
#pragma unroll
  for (int c = 0; c < 16; c++) {
    r1 += acc[c] * avs[c0 + c];
    r2 += acc[c] * avd[c0 + c];
  }
  red1[w][lane] = r1;
  red2[w][lane] = r2;
#pragma unroll
  for (int c = 0; c < 16; c++) tile[(c0 + c) * 65 + lane] = acc[c];
  __syncthreads();
  if (w == 0 && node < cBN) {
    ssrc[node] = red1[0][lane] + red1[1][lane] + red1[2][lane] + red1[3][lane];
    sdst[node] = red2[0][lane] + red2[1][lane] + red2[2][lane] + red2[3][lane];
  }
  for (int r = w; r < 64; r += 4) {
    if (base + r < cBN) hw[(size_t)(base + r) * 64 + lane] = tile[lane * 65 + r];
  }
}

// ---------------- hop aggregate (lane=H) + larval fused at hop 0 ----------------
__global__ __launch_bounds__(256) void k_hop_agg(const float* hw, const float* ssrc,
                                                 const float* sdst, const int* row_ptr,
                                                 const int* esrc, const float* gcsr,
                                                 const float* h, float* cur_t, float* z_t,
                                                 float* agg_t, int hop) {
  int w = threadIdx.x >> 6, lane = threadIdx.x & 63;
  int node = blockIdx.x * 4 + w;
  int b = node / cN, n = node - b * cN;
  int r0 = row_ptr[n], r1 = row_ptr[n + 1];
  const float* sb = ssrc + (size_t)b * cN;
  float sd = sdst[node];
  float m = -INFINITY;
  for (int e = r0 + lane; e < r1; e += 64) {
    float ev = sb[esrc[e]] + sd;
    ev = ev > 0.f ? ev : 0.2f * ev;
    m = fmaxf(m, ev);
  }
  m = wmax(m);
  float den = 0.f, num = 0.f, lacc = 0.f;
  const float* hwb = hw + (size_t)b * cN * cH;
  const float* hb = h + (size_t)b * cN * cH;
  for (int e = r0; e < r1; e++) {
    int s = esrc[e];
    float ev = sb[s] + sd;
    ev = ev > 0.f ? ev : 0.2f * ev;
    float wgt = expf(ev - m);
    den += wgt;
    num += wgt * hwb[(size_t)s * cH + lane];
    if (hop == 0) lacc += gcsr[e] * hb[(size_t)s * cH + lane];
  }
  float cv = num / (den + 1e-16f);
  size_t zi = (size_t)(64 + lane) * cBN + node;
  if (hop < 2) cur_t[(size_t)lane * cBN + node] = cv;
  if (hop == 0) {
    z_t[zi] = cv;
    agg_t[(size_t)lane * cBN + node] = lacc;
  } else {
    z_t[zi] += cv;
  }
}

// ---------------- fused cell: lane=node, 4 waves split 64 cols ----------------
__global__ __launch_bounds__(256) void k_cell_t(fp x, int t, float* z_t, float* h,
                                                const float* agg_t, const int* row_ptr, fp W_lt,
                                                fp W_tau, fp b_tau, fp W_g, fp b_g, fp gamma,
                                                fp beta, fp c_enc, fp W_enc, fp b_enc, fp cdec,
                                                fp W_dec, fp b_dec, float* out) {
  __shared__ float tile[64 * 65];
  __shared__ float redm[4][64], redv[4][64];
  __shared__ float redp[4][3][64];
  int w = threadIdx.x >> 6, lane = threadIdx.x & 63;
  int base = blockIdx.x * 64, node = base + lane;
  int nd = node < cBN ? node : cBN - 1;
  int b = nd / cN, n = nd - b * cN;
  int c0 = __builtin_amdgcn_readfirstlane(w * 16);
  const float* xp = x + (((size_t)b * cT + t) * cN + n) * cF;
  float xv[16];
#pragma unroll
  for (int f = 0; f < 16; f++) xv[f] = xp[f];
  float deg = (float)(row_ptr[n + 1] - row_ptr[n]);
  // Phase A: finalize p rows: p = khop_sum/3 + (agg @ W_lt)/(deg+1)
  {
    float pacc[16];
#pragma unroll
    for (int c = 0; c < 16; c++) pacc[c] = 0.f;
    for (int i = 0; i < 64; i++) {
      float av = agg_t[(size_t)i * cBN + nd];
#pragma unroll
      for (int c = 0; c < 16; c++) pacc[c] += av * W_lt[i * 64 + c0 + c];
    }
    float idp = 1.f / (deg + 1.f);
    if (node < cBN) {
#pragma unroll
      for (int c = 0; c < 16; c++) {
        size_t zi = (size_t)(64 + c0 + c) * cBN + node;
        z_t[zi] = z_t[zi] * (1.f / 3.f) + pacc[c] * idp;
      }
    }
  }
  __syncthreads();  // all p rows visible block-wide (columns are block-private)
  // Phase B: tau/g matvecs over z = [h(64) | env(5) | p(64)]
  float accT[16], accG[16];
#pragma unroll
  for (int c = 0; c < 16; c++) {
    accT[c] = b_tau[c0 + c];
    accG[c] = b_g[c0 + c];
  }
  for (int k = 0; k < 64; k++) {
    float zv = z_t[(size_t)k * cBN + nd];
#pragma unroll
    for (int c = 0; c < 16; c++) {
      accT[c] += zv * W_tau[k * 64 + c0 + c];
      accG[c] += zv * W_g[k * 64 + c0 + c];
    }
  }
#pragma unroll
  for (int j = 0; j < 5; j++) {
    float zv = xv[8 + j];
    int r = 64 + j;
#pragma unroll
    for (int c = 0; c < 16; c++) {
      accT[c] += zv * W_tau[r * 64 + c0 + c];
      accG[c] += zv * W_g[r * 64 + c0 + c];
    }
  }
  for (int k = 0; k < 64; k++) {
    float zv = z_t[(size_t)(64 + k) * cBN + nd];
    int r = 69 + k;
#pragma unroll
    for (int c = 0; c < 16; c++) {
      accT[c] += zv * W_tau[r * 64 + c0 + c];
      accG[c] += zv * W_g[r * 64 + c0 + c];
    }
  }
  // Phase C: liquid update + LayerNorm (reductions per-lane + LDS across waves)
  float pm = 0.f;
#pragma unroll
  for (int c = 0; c < 16; c++) {
    float hcur = z_t[(size_t)(c0 + c) * cBN + nd];
    float tau = 1.f + 9.f / (1.f + expf(-accT[c]));
    float g = tanhf(accG[c]);
    float v = hcur + 0.25f * (g - hcur) / tau;
    accT[c] = v;
    pm += v;
  }
  redm[w][lane] = pm;
  __syncthreads();
  float mu = (redm[0][lane] + redm[1][lane] + redm[2][lane] + redm[3][lane]) * (1.f / 64.f);
  float pv = 0.f;
#pragma unroll
  for (int c = 0; c < 16; c++) {
    float d = accT[c] - mu;
    pv += d * d;
  }
  redv[w][lane] = pv;
  __syncthreads();
  float var = (redv[0][lane] + redv[1][lane] + redv[2][lane] + redv[3][lane]) * (1.f / 64.f);
  float rstd = rsqrtf(var + 1e-5f);
#pragma unroll
  for (int c = 0; c < 16; c++) accT[c] = (accT[c] - mu) * rstd * gamma[c0 + c] + beta[c0 + c];
  // encoder u added in
  float ec0 = c_enc[0], ec7 = c_enc[7];
  float inv_e = 7.f / (ec7 - ec0);
  for (int f = 0; f < 16; f++) {
#pragma unroll
    for (int cb = 0; cb < 8; cb++) {
      float d = (xv[f] - c_enc[cb]) * inv_e;
      float ph = __expf(-d * d);
      int j = f * 8 + cb;
#pragma unroll
      for (int c = 0; c < 16; c++) accT[c] += ph * W_enc[j * 64 + c0 + c];
    }
  }
#pragma unroll
  for (int c = 0; c < 16; c++) accT[c] += b_enc[c0 + c];
  // Phase D: store h (both layouts) + decoder
  if (node < cBN) {
#pragma unroll
    for (int c = 0; c < 16; c++) z_t[(size_t)(c0 + c) * cBN + node] = accT[c];
  }
#pragma unroll
  for (int c = 0; c < 16; c++) tile[(c0 + c) * 65 + lane] = accT[c];
  float dc0 = cdec[0], dc7 = cdec[7];
  float inv_d = 7.f / (dc7 - dc0);
  float p0 = 0.f, p1 = 0.f, p2 = 0.f;
#pragma unroll
  for (int c = 0; c < 16; c++) {
#pragma unroll
    for (int j = 0; j < 8; j++) {
      float dd = (accT[c] - cdec[j]) * inv_d;
      float ph = __expf(-dd * dd);
      int bb = ((c0 + c) * 8 + j) * 3;
      p0 += ph * W_dec[bb];
      p1 += ph * W_dec[bb + 1];
      p2 += ph * W_dec[bb + 2];
    }
  }
  redp[w][0][lane] = p0;
  redp[w][1][lane] = p1;
  redp[w][2][lane] = p2;
  __syncthreads();
  for (int r = w; r < 64; r += 4) {
    if (base + r < cBN) h[(size_t)(base + r) * 64 + lane] = tile[lane * 65 + r];
  }
  if (w == 0 && node < cBN) {
    float v0 = redp[0][0][lane] + redp[1][0][lane] + redp[2][0][lane] + redp[3][0][lane] + b_dec[0];
    float v1 = redp[0][1][lane] + redp[1][1][lane] + redp[2][1][lane] + redp[3][1][lane] + b_dec[1];
    float v2 = redp[0][2][lane] + redp[1][2][lane] + redp[2][2][lane] + redp[3][2][lane] + b_dec[2];
    size_t ob = (((size_t)b * cT + t) * cN + n) * 3;
    out[ob] = fmaxf(v0, 0.f) + log1pf(expf(-fabsf(v0)));
    out[ob + 1] = fmaxf(v1, 0.f) + log1pf(expf(-fabsf(v1)));
    out[ob + 2] = fmaxf(v2, 0.f) + log1pf(expf(-fabsf(v2)));
  }
}

extern "C" void kernel_launch(void* const* d_in, const int* in_sizes, int n_in, void* d_out,
                              int out_size, void* d_ws, size_t ws_size, hipStream_t stream) {
  fp x = (fp)d_in[0];
  fp edge_attr = (fp)d_in[1];
  fp c_enc = (fp)d_in[2];
  fp W_enc = (fp)d_in[3];
  fp b_enc = (fp)d_in[4];
  fp W_hop = (fp)d_in[5];
  fp a_src = (fp)d_in[6];
  fp a_dst = (fp)d_in[7];
  fp w_lt1 = (fp)d_in[8];
  fp b_lt1 = (fp)d_in[9];
  fp w_lt2 = (fp)d_in[10];
  fp b_lt2 = (fp)d_in[11];
  fp W_lt = (fp)d_in[12];
  fp W_tau = (fp)d_in[13];
  fp b_tau = (fp)d_in[14];
  fp W_g = (fp)d_in[15];
  fp b_g = (fp)d_in[16];
  fp gamma = (fp)d_in[17];
  fp beta = (fp)d_in[18];
  fp c_dec = (fp)d_in[19];
  fp W_dec = (fp)d_in[20];
  fp b_dec = (fp)d_in[21];
  fp h0 = (fp)d_in[22];
  const int* eidx = (const int*)d_in[23];
  const int* esrc_in = eidx;
  const int* edst_in = eidx + cE;

  float* fws = (float*)d_ws;
  float* z_t = fws;    fws += 128 * cBN;  // rows 0..63 h_t, 64..127 p
  float* cur_t = fws;  fws += 64 * cBN;
  float* hw = fws;     fws += cBNH;
  float* h = fws;      fws += cBNH;
  float* agg_t = fws;  fws += 64 * cBN;
  float* ssrc = fws;   fws += cBN;
  float* sdst = fws;   fws += cBN;
  float* gcsr = fws;   fws += cE;
  int* iws = (int*)fws;
  int* esrc = iws;     iws += cE;
  int* row_ptr = iws;  iws += cN + 1;
  int* cursor = iws;   iws += cN;
  int* counts = iws;   iws += cN;

  k_zero_i32<<<(cN + 255) / 256, 256, 0, stream>>>(counts, cN);
  k_count<<<(cE + 255) / 256, 256, 0, stream>>>(edst_in, counts);
  k_scan<<<1, 1024, 0, stream>>>(counts, row_ptr, cursor);
  k_scatter<<<(cE + 255) / 256, 256, 0, stream>>>(esrc_in, edst_in, edge_attr, w_lt1, b_lt1,
                                                  w_lt2, b_lt2, cursor, esrc, gcsr);
  k_init<<<(cBNH + 255) / 256, 256, 0, stream>>>(h, z_t, h0);

  for (int t = 0; t < cT; t++) {
    for (int k = 0; k < cK; k++) {
      k_hop_mat_t<<<NBLK, 256, 0, stream>>>(k == 0 ? z_t : cur_t, W_hop + (size_t)k * cH * cH,
                                            a_src + k * cH, a_dst + k * cH, hw, ssrc, sdst);
      k_hop_agg<<<cBN / 4, 256, 0, stream>>>(hw, ssrc, sdst, row_ptr, esrc, gcsr, h, cur_t, z_t,
                                             agg_t, k);
    }
    k_cell_t<<<NBLK, 256, 0, stream>>>(x, t, z_t, h, agg_t, row_ptr, W_lt, W_tau, b_tau, W_g,
                                       b_g, gamma, beta, c_enc, W_enc, b_enc, c_dec, W_dec,
                                       b_dec, (float*)d_out);
  }
}

// Round 5
// 1337.912 us; speedup vs baseline: 1.0807x; 1.0807x over previous
//
#include <hip/hip_runtime.h>
#include <math.h>

// SeaLiceGLKAN — fp32 in/out. lane=node register-GEMM with (nodegroup × colchunk)
// wave parallelism for dense parts; lane=H for edge gathers.
// z_t layout: [row][node], rows 0..63 = h transposed, rows 64..127 = p.

constexpr int cB = 2, cT = 4, cN = 10000, cF = 16, cH = 64, cE = 160000, cNB = 8, cK = 3;
constexpr int cBN = cB * cN;    // 20000
constexpr int cBNH = cBN * cH;  // 1,280,000
constexpr int NBLK = (cBN + 63) / 64;  // 313 nodegroups of 64 nodes

typedef const float* fp;

__device__ __forceinline__ float wmax(float v) {
#pragma unroll
  for (int o = 1; o < 64; o <<= 1) v = fmaxf(v, __shfl_xor(v, o, 64));
  return v;
}

// ---------------- CSR build ----------------
__global__ void k_zero_i32(int* p, int n) {
  int i = blockIdx.x * 256 + threadIdx.x;
  if (i < n) p[i] = 0;
}

__global__ void k_count(const int* dst, int* counts) {
  int e = blockIdx.x * 256 + threadIdx.x;
  if (e < cE) atomicAdd(&counts[dst[e]], 1);
}

__global__ void k_scan(const int* counts, int* row_ptr, int* cursor) {
  __shared__ int part[1024];
  int t = threadIdx.x;
  const int CH = (cN + 1023) / 1024;  // 10
  int s = 0;
  for (int i = 0; i < CH; i++) {
    int idx = t * CH + i;
    if (idx < cN) s += counts[idx];
  }
  part[t] = s;
  __syncthreads();
  for (int off = 1; off < 1024; off <<= 1) {
    int v = (t >= off) ? part[t - off] : 0;
    __syncthreads();
    part[t] += v;
    __syncthreads();
  }
  int excl = (t == 0) ? 0 : part[t - 1];
  for (int i = 0; i < CH; i++) {
    int idx = t * CH + i;
    if (idx < cN) {
      row_ptr[idx] = excl;
      cursor[idx] = excl;
      excl += counts[idx];
    }
  }
  if (t == 1023) row_ptr[cN] = part[1023];
}

__global__ void k_scatter(const int* src, const int* dst, fp ea, fp w1, fp b1, fp w2, fp b2,
                          int* cursor, int* esrc, float* gcsr) {
  int e = blockIdx.x * 256 + threadIdx.x;
  if (e >= cE) return;
  float a0 = ea[e * 4 + 0], a1 = ea[e * 4 + 1], a2 = ea[e * 4 + 2], a3 = ea[e * 4 + 3];
  float acc = b2[0];
#pragma unroll
  for (int j = 0; j < 16; j++) {
    float tv = b1[j] + a0 * w1[j] + a1 * w1[16 + j] + a2 * w1[32 + j] + a3 * w1[48 + j];
    acc += tanhf(tv) * w2[j];
  }
  float g = 1.f / (1.f + expf(-acc));
  int p = atomicAdd(&cursor[dst[e]], 1);
  esrc[p] = src[e];
  gcsr[p] = g;
}

__global__ void k_init(float* h, float* z_t, fp h0) {
  int i = blockIdx.x * 256 + threadIdx.x;
  if (i < cBNH) {
    h[i] = h0[i & 63];
    z_t[i] = h0[i / cBN];  // rows 0..63 of z_t = h transposed
  }
}

// ---------------- hop matvec: lane=node, 4 waves split 64 cols ----------------
__global__ __launch_bounds__(256) void k_hop_mat_t(const float* vin_t, fp Wh, fp avs, fp avd,
                                                   float* hw, float* ssrc, float* sdst) {
  __shared__ float tile[64 * 65];
  __shared__ float red1[4][64], red2[4][64];
  int w = threadIdx.x >> 6, lane = threadIdx.x & 63;
  int base = blockIdx.x * 64, node = base + lane;
  int nd = node < cBN ? node : cBN - 1;
  int c0 = __builtin_amdgcn_readfirstlane(w * 16);  // wave-uniform column offset
  float acc[16];
#pragma unroll
  for (int c = 0; c < 16; c++) acc[c] = 0.f;
  for (int i = 0; i < 64; i++) {
    float cv = vin_t[(size_t)i * cBN + nd];
#pragma unroll
    for (int c = 0; c < 16; c++) acc[c] += cv * Wh[i * 64 + c0 + c];
  }
  float r1 = 0.f, r2 = 0.f;
#pragma unroll
  for (int c = 0; c < 16; c++) {
    r1 += acc[c] * avs[c0 + c];
    r2 += acc[c] * avd[c0 + c];
  }
  red1[w][lane] = r1;
  red2[w][lane] = r2;
#pragma unroll
  for (int c = 0; c < 16; c++) tile[(c0 + c) * 65 + lane] = acc[c];
  __syncthreads();
  if (w == 0 && node < cBN) {
    ssrc[node] = red1[0][lane] + red1[1][lane] + red1[2][lane] + red1[3][lane];
    sdst[node] = red2[0][lane] + red2[1][lane] + red2[2][lane] + red2[3][lane];
  }
  for (int r = w; r < 64; r += 4) {
    if (base + r < cBN) hw[(size_t)(base + r) * 64 + lane] = tile[lane * 65 + r];
  }
}

// ---------------- hop aggregate (lane=H) + larval fused at hop 0 ----------------
__global__ __launch_bounds__(256) void k_hop_agg(const float* hw, const float* ssrc,
                                                 const float* sdst, const int* row_ptr,
                                                 const int* esrc, const float* gcsr,
                                                 const float* h, float* cur_t, float* z_t,
                                                 float* agg_t, int hop) {
  int w = threadIdx.x >> 6, lane = threadIdx.x & 63;
  int node = blockIdx.x * 4 + w;
  int b = node / cN, n = node - b * cN;
  int r0 = row_ptr[n], r1 = row_ptr[n + 1];
  const float* sb = ssrc + (size_t)b * cN;
  float sd = sdst[node];
  float m = -INFINITY;
  for (int e = r0 + lane; e < r1; e += 64) {
    float ev = sb[esrc[e]] + sd;
    ev = ev > 0.f ? ev : 0.2f * ev;
    m = fmaxf(m, ev);
  }
  m = wmax(m);
  float den = 0.f, num = 0.f, lacc = 0.f;
  const float* hwb = hw + (size_t)b * cN * cH;
  const float* hb = h + (size_t)b * cN * cH;
  for (int e = r0; e < r1; e++) {
    int s = esrc[e];
    float ev = sb[s] + sd;
    ev = ev > 0.f ? ev : 0.2f * ev;
    float wgt = expf(ev - m);
    den += wgt;
    num += wgt * hwb[(size_t)s * cH + lane];
    if (hop == 0) lacc += gcsr[e] * hb[(size_t)s * cH + lane];
  }
  float cv = num / (den + 1e-16f);
  size_t zi = (size_t)(64 + lane) * cBN + node;
  if (hop < 2) cur_t[(size_t)lane * cBN + node] = cv;
  if (hop == 0) {
    z_t[zi] = cv;
    agg_t[(size_t)lane * cBN + node] = lacc;
  } else {
    z_t[zi] += cv;
  }
}

// ---------------- p finalize: p = khop_sum/3 + (agg @ W_lt)/(deg+1) ----------------
__global__ __launch_bounds__(256) void k_pfin(float* z_t, const float* agg_t, const int* row_ptr,
                                              fp W_lt) {
  int w = threadIdx.x >> 6, lane = threadIdx.x & 63;
  int node = blockIdx.x * 64 + lane;
  int nd = node < cBN ? node : cBN - 1;
  int b = nd / cN, n = nd - b * cN;
  int c0 = __builtin_amdgcn_readfirstlane(w * 16);
  float pacc[16];
#pragma unroll
  for (int c = 0; c < 16; c++) pacc[c] = 0.f;
  for (int i = 0; i < 64; i++) {
    float av = agg_t[(size_t)i * cBN + nd];
#pragma unroll
    for (int c = 0; c < 16; c++) pacc[c] += av * W_lt[i * 64 + c0 + c];
  }
  float idp = 1.f / ((float)(row_ptr[n + 1] - row_ptr[n]) + 1.f);
  if (node < cBN) {
#pragma unroll
    for (int c = 0; c < 16; c++) {
      size_t zi = (size_t)(64 + c0 + c) * cBN + node;
      z_t[zi] = z_t[zi] * (1.f / 3.f) + pacc[c] * idp;
    }
  }
}

// ---------------- heavy matvecs: tau/g over z(133), encoder u over phi(128) ----------------
// wave = (nodegroup, sub); sub 0..7 -> [tau|g] colchunk, sub 8..11 -> u colchunk
__global__ __launch_bounds__(256) void k_zmat(const float* z_t, fp x, int t, fp W_tau, fp b_tau,
                                              fp W_g, fp b_g, fp c_enc, fp W_enc, fp b_enc,
                                              float* tg_t, float* u_t) {
  int w = threadIdx.x >> 6, lane = threadIdx.x & 63;
  int wid = blockIdx.x * 4 + w;
  int ng = wid / 12, sub = wid - ng * 12;
  int node = ng * 64 + lane;
  int nd = node < cBN ? node : cBN - 1;
  int b = nd / cN, n = nd - b * cN;
  const float* xp = x + (((size_t)b * cT + t) * cN + n) * cF;
  float acc[16];
  if (sub < 8) {
    int c0 = __builtin_amdgcn_readfirstlane(sub * 16);  // 0..127 across [tau|g]
    const float* W = (c0 < 64) ? W_tau : W_g;
    const float* bias = (c0 < 64) ? b_tau : b_g;
    int cc = c0 & 63;
#pragma unroll
    for (int c = 0; c < 16; c++) acc[c] = bias[cc + c];
    for (int k = 0; k < 64; k++) {
      float zv = z_t[(size_t)k * cBN + nd];
#pragma unroll
      for (int c = 0; c < 16; c++) acc[c] += zv * W[k * 64 + cc + c];
    }
#pragma unroll
    for (int j = 0; j < 5; j++) {
      float zv = xp[8 + j];
      int r = 64 + j;
#pragma unroll
      for (int c = 0; c < 16; c++) acc[c] += zv * W[r * 64 + cc + c];
    }
    for (int k = 0; k < 64; k++) {
      float zv = z_t[(size_t)(64 + k) * cBN + nd];
      int r = 69 + k;
#pragma unroll
      for (int c = 0; c < 16; c++) acc[c] += zv * W[r * 64 + cc + c];
    }
    if (node < cBN) {
#pragma unroll
      for (int c = 0; c < 16; c++) tg_t[(size_t)(c0 + c) * cBN + node] = acc[c];
    }
  } else {
    int cu = __builtin_amdgcn_readfirstlane((sub - 8) * 16);
    float ec0 = c_enc[0], ec7 = c_enc[7];
    float inv_e = 7.f / (ec7 - ec0);
#pragma unroll
    for (int c = 0; c < 16; c++) acc[c] = b_enc[cu + c];
    for (int f = 0; f < 16; f++) {
      float xv = xp[f];
#pragma unroll
      for (int cb = 0; cb < 8; cb++) {
        float d = (xv - c_enc[cb]) * inv_e;
        float ph = __expf(-d * d);
        const float* Wr = W_enc + (f * 8 + cb) * 64 + cu;
#pragma unroll
        for (int c = 0; c < 16; c++) acc[c] += ph * Wr[c];
      }
    }
    if (node < cBN) {
#pragma unroll
      for (int c = 0; c < 16; c++) u_t[(size_t)(cu + c) * cBN + node] = acc[c];
    }
  }
}

// ---------------- light cell: liquid + LN + u + decoder + h transpose ----------------
__global__ __launch_bounds__(256) void k_cell2(float* z_t, float* h, const float* tg_t,
                                               const float* u_t, fp gamma, fp beta, fp cdec,
                                               fp W_dec, fp b_dec, int t, float* out) {
  __shared__ float tile[64 * 65];
  __shared__ float redm[4][64], redv[4][64];
  __shared__ float redp[4][3][64];
  int w = threadIdx.x >> 6, lane = threadIdx.x & 63;
  int base = blockIdx.x * 64, node = base + lane;
  int nd = node < cBN ? node : cBN - 1;
  int b = nd / cN, n = nd - b * cN;
  int c0 = __builtin_amdgcn_readfirstlane(w * 16);
  float acc[16];
  float pm = 0.f;
#pragma unroll
  for (int c = 0; c < 16; c++) {
    float hcur = z_t[(size_t)(c0 + c) * cBN + nd];
    float at = tg_t[(size_t)(c0 + c) * cBN + nd];
    float ag = tg_t[(size_t)(64 + c0 + c) * cBN + nd];
    float tau = 1.f + 9.f / (1.f + __expf(-at));
    float g = tanhf(ag);
    float v = hcur + 0.25f * (g - hcur) / tau;
    acc[c] = v;
    pm += v;
  }
  redm[w][lane] = pm;
  __syncthreads();
  float mu = (redm[0][lane] + redm[1][lane] + redm[2][lane] + redm[3][lane]) * (1.f / 64.f);
  float pv = 0.f;
#pragma unroll
  for (int c = 0; c < 16; c++) {
    float d = acc[c] - mu;
    pv += d * d;
  }
  redv[w][lane] = pv;
  __syncthreads();
  float var = (redv[0][lane] + redv[1][lane] + redv[2][lane] + redv[3][lane]) * (1.f / 64.f);
  float rstd = rsqrtf(var + 1e-5f);
#pragma unroll
  for (int c = 0; c < 16; c++) {
    acc[c] = (acc[c] - mu) * rstd * gamma[c0 + c] + beta[c0 + c] +
             u_t[(size_t)(c0 + c) * cBN + nd];
  }
  // store h (col-major) + stage transpose
  if (node < cBN) {
#pragma unroll
    for (int c = 0; c < 16; c++) z_t[(size_t)(c0 + c) * cBN + node] = acc[c];
  }
#pragma unroll
  for (int c = 0; c < 16; c++) tile[(c0 + c) * 65 + lane] = acc[c];
  // decoder fastkan + softplus
  float dc0 = cdec[0], dc7 = cdec[7];
  float inv_d = 7.f / (dc7 - dc0);
  float p0 = 0.f, p1 = 0.f, p2 = 0.f;
#pragma unroll
  for (int c = 0; c < 16; c++) {
#pragma unroll
    for (int j = 0; j < 8; j++) {
      float dd = (acc[c] - cdec[j]) * inv_d;
      float ph = __expf(-dd * dd);
      int bb = ((c0 + c) * 8 + j) * 3;
      p0 += ph * W_dec[bb];
      p1 += ph * W_dec[bb + 1];
      p2 += ph * W_dec[bb + 2];
    }
  }
  redp[w][0][lane] = p0;
  redp[w][1][lane] = p1;
  redp[w][2][lane] = p2;
  __syncthreads();
  for (int r = w; r < 64; r += 4) {
    if (base + r < cBN) h[(size_t)(base + r) * 64 + lane] = tile[lane * 65 + r];
  }
  if (w == 0 && node < cBN) {
    float v0 = redp[0][0][lane] + redp[1][0][lane] + redp[2][0][lane] + redp[3][0][lane] + b_dec[0];
    float v1 = redp[0][1][lane] + redp[1][1][lane] + redp[2][1][lane] + redp[3][1][lane] + b_dec[1];
    float v2 = redp[0][2][lane] + redp[1][2][lane] + redp[2][2][lane] + redp[3][2][lane] + b_dec[2];
    size_t ob = (((size_t)b * cT + t) * cN + n) * 3;
    out[ob] = fmaxf(v0, 0.f) + log1pf(expf(-fabsf(v0)));
    out[ob + 1] = fmaxf(v1, 0.f) + log1pf(expf(-fabsf(v1)));
    out[ob + 2] = fmaxf(v2, 0.f) + log1pf(expf(-fabsf(v2)));
  }
}

extern "C" void kernel_launch(void* const* d_in, const int* in_sizes, int n_in, void* d_out,
                              int out_size, void* d_ws, size_t ws_size, hipStream_t stream) {
  fp x = (fp)d_in[0];
  fp edge_attr = (fp)d_in[1];
  fp c_enc = (fp)d_in[2];
  fp W_enc = (fp)d_in[3];
  fp b_enc = (fp)d_in[4];
  fp W_hop = (fp)d_in[5];
  fp a_src = (fp)d_in[6];
  fp a_dst = (fp)d_in[7];
  fp w_lt1 = (fp)d_in[8];
  fp b_lt1 = (fp)d_in[9];
  fp w_lt2 = (fp)d_in[10];
  fp b_lt2 = (fp)d_in[11];
  fp W_lt = (fp)d_in[12];
  fp W_tau = (fp)d_in[13];
  fp b_tau = (fp)d_in[14];
  fp W_g = (fp)d_in[15];
  fp b_g = (fp)d_in[16];
  fp gamma = (fp)d_in[17];
  fp beta = (fp)d_in[18];
  fp c_dec = (fp)d_in[19];
  fp W_dec = (fp)d_in[20];
  fp b_dec = (fp)d_in[21];
  fp h0 = (fp)d_in[22];
  const int* eidx = (const int*)d_in[23];
  const int* esrc_in = eidx;
  const int* edst_in = eidx + cE;

  float* fws = (float*)d_ws;
  float* z_t = fws;    fws += 128 * cBN;  // rows 0..63 h_t, 64..127 p
  float* cur_t = fws;  fws += 64 * cBN;   // also aliased as u_t after hops
  float* hw = fws;     fws += cBNH;
  float* h = fws;      fws += cBNH;
  float* agg_t = fws;  fws += 64 * cBN;
  float* tg_t = fws;   fws += 128 * cBN;
  float* ssrc = fws;   fws += cBN;
  float* sdst = fws;   fws += cBN;
  float* gcsr = fws;   fws += cE;
  int* iws = (int*)fws;
  int* esrc = iws;     iws += cE;
  int* row_ptr = iws;  iws += cN + 1;
  int* cursor = iws;   iws += cN;
  int* counts = iws;   iws += cN;
  float* u_t = cur_t;  // cur_t dead after hop-2 matvec; u_t live zmat->cell2

  k_zero_i32<<<(cN + 255) / 256, 256, 0, stream>>>(counts, cN);
  k_count<<<(cE + 255) / 256, 256, 0, stream>>>(edst_in, counts);
  k_scan<<<1, 1024, 0, stream>>>(counts, row_ptr, cursor);
  k_scatter<<<(cE + 255) / 256, 256, 0, stream>>>(esrc_in, edst_in, edge_attr, w_lt1, b_lt1,
                                                  w_lt2, b_lt2, cursor, esrc, gcsr);
  k_init<<<(cBNH + 255) / 256, 256, 0, stream>>>(h, z_t, h0);

  for (int t = 0; t < cT; t++) {
    for (int k = 0; k < cK; k++) {
      k_hop_mat_t<<<NBLK, 256, 0, stream>>>(k == 0 ? z_t : cur_t, W_hop + (size_t)k * cH * cH,
                                            a_src + k * cH, a_dst + k * cH, hw, ssrc, sdst);
      k_hop_agg<<<cBN / 4, 256, 0, stream>>>(hw, ssrc, sdst, row_ptr, esrc, gcsr, h, cur_t, z_t,
                                             agg_t, k);
    }
    k_pfin<<<NBLK, 256, 0, stream>>>(z_t, agg_t, row_ptr, W_lt);
    k_zmat<<<(NBLK * 12 + 3) / 4, 256, 0, stream>>>(z_t, x, t, W_tau, b_tau, W_g, b_g, c_enc,
                                                    W_enc, b_enc, tg_t, u_t);
    k_cell2<<<NBLK, 256, 0, stream>>>(z_t, h, tg_t, u_t, gamma, beta, c_dec, W_dec, b_dec, t,
                                      (float*)d_out);
  }
}

// Round 6
// 1149.293 us; speedup vs baseline: 1.2580x; 1.1641x over previous
//
#include <hip/hip_runtime.h>
#include <math.h>

// SeaLiceGLKAN — fp32 in/out. lane=node register-GEMM for dense parts (weights via
// wave-uniform scalar loads), lane=H for edge gathers. Gather outputs are node-major
// (coalesced); consumers transpose through LDS. z_t layout: [row][node] col-major,
// rows 0..63 = h transposed, rows 64..127 = p.

constexpr int cB = 2, cT = 4, cN = 10000, cF = 16, cH = 64, cE = 160000, cNB = 8, cK = 3;
constexpr int cBN = cB * cN;    // 20000
constexpr int cBNH = cBN * cH;  // 1,280,000
constexpr int NBLK = (cBN + 63) / 64;  // 313 nodegroups of 64 nodes

typedef const float* fp;

__device__ __forceinline__ float wmax(float v) {
#pragma unroll
  for (int o = 1; o < 64; o <<= 1) v = fmaxf(v, __shfl_xor(v, o, 64));
  return v;
}

// ---------------- CSR build ----------------
__global__ void k_zero_i32(int* p, int n) {
  int i = blockIdx.x * 256 + threadIdx.x;
  if (i < n) p[i] = 0;
}

__global__ void k_count(const int* dst, int* counts) {
  int e = blockIdx.x * 256 + threadIdx.x;
  if (e < cE) atomicAdd(&counts[dst[e]], 1);
}

__global__ void k_scan(const int* counts, int* row_ptr, int* cursor) {
  __shared__ int part[1024];
  int t = threadIdx.x;
  const int CH = (cN + 1023) / 1024;  // 10
  int s = 0;
  for (int i = 0; i < CH; i++) {
    int idx = t * CH + i;
    if (idx < cN) s += counts[idx];
  }
  part[t] = s;
  __syncthreads();
  for (int off = 1; off < 1024; off <<= 1) {
    int v = (t >= off) ? part[t - off] : 0;
    __syncthreads();
    part[t] += v;
    __syncthreads();
  }
  int excl = (t == 0) ? 0 : part[t - 1];
  for (int i = 0; i < CH; i++) {
    int idx = t * CH + i;
    if (idx < cN) {
      row_ptr[idx] = excl;
      cursor[idx] = excl;
      excl += counts[idx];
    }
  }
  if (t == 1023) row_ptr[cN] = part[1023];
}

__global__ void k_scatter(const int* src, const int* dst, fp ea, fp w1, fp b1, fp w2, fp b2,
                          int* cursor, int* esrc, float* gcsr) {
  int e = blockIdx.x * 256 + threadIdx.x;
  if (e >= cE) return;
  float a0 = ea[e * 4 + 0], a1 = ea[e * 4 + 1], a2 = ea[e * 4 + 2], a3 = ea[e * 4 + 3];
  float acc = b2[0];
#pragma unroll
  for (int j = 0; j < 16; j++) {
    float tv = b1[j] + a0 * w1[j] + a1 * w1[16 + j] + a2 * w1[32 + j] + a3 * w1[48 + j];
    acc += tanhf(tv) * w2[j];
  }
  float g = 1.f / (1.f + expf(-acc));
  int p = atomicAdd(&cursor[dst[e]], 1);
  esrc[p] = src[e];
  gcsr[p] = g;
}

__global__ void k_init(float* h, float* z_t, fp h0) {
  int i = blockIdx.x * 256 + threadIdx.x;
  if (i < cBNH) {
    h[i] = h0[i & 63];
    z_t[i] = h0[i / cBN];  // rows 0..63 of z_t = h transposed
  }
}

// ---------------- hop matvec: node-major input via LDS, lane=node ----------------
__global__ __launch_bounds__(256) void k_hop_mat_t(const float* vin_nm, fp Wh, fp avs, fp avd,
                                                   float* hw, float* ssrc, float* sdst) {
  __shared__ float tin[64 * 65];
  __shared__ float tout[64 * 65];
  __shared__ float red1[4][64], red2[4][64];
  int w = threadIdx.x >> 6, lane = threadIdx.x & 63;
  int base = blockIdx.x * 64, node = base + lane;
  int c0 = __builtin_amdgcn_readfirstlane(w * 16);  // wave-uniform column offset
  // stage input tile: thread -> (node tn, 16-float chunk f0), coalesced float4 loads
  {
    int tn = threadIdx.x >> 2, f0 = (threadIdx.x & 3) * 16;
    int gn = base + tn;
    if (gn >= cBN) gn = cBN - 1;
    const float4* vsrc = (const float4*)(vin_nm + (size_t)gn * 64 + f0);
#pragma unroll
    for (int q = 0; q < 4; q++) {
      float4 v = vsrc[q];
      tin[tn * 65 + f0 + q * 4 + 0] = v.x;
      tin[tn * 65 + f0 + q * 4 + 1] = v.y;
      tin[tn * 65 + f0 + q * 4 + 2] = v.z;
      tin[tn * 65 + f0 + q * 4 + 3] = v.w;
    }
  }
  __syncthreads();
  float acc[16];
#pragma unroll
  for (int c = 0; c < 16; c++) acc[c] = 0.f;
  for (int i = 0; i < 64; i++) {
    float cv = tin[lane * 65 + i];
#pragma unroll
    for (int c = 0; c < 16; c++) acc[c] += cv * Wh[i * 64 + c0 + c];
  }
  float r1 = 0.f, r2 = 0.f;
#pragma unroll
  for (int c = 0; c < 16; c++) {
    r1 += acc[c] * avs[c0 + c];
    r2 += acc[c] * avd[c0 + c];
  }
  red1[w][lane] = r1;
  red2[w][lane] = r2;
#pragma unroll
  for (int c = 0; c < 16; c++) tout[(c0 + c) * 65 + lane] = acc[c];
  __syncthreads();
  if (w == 0 && node < cBN) {
    ssrc[node] = red1[0][lane] + red1[1][lane] + red1[2][lane] + red1[3][lane];
    sdst[node] = red2[0][lane] + red2[1][lane] + red2[2][lane] + red2[3][lane];
  }
  for (int r = w; r < 64; r += 4) {
    if (base + r < cBN) hw[(size_t)(base + r) * 64 + lane] = tout[lane * 65 + r];
  }
}

// ---------------- hop aggregate (lane=H) + larval fused at hop 0 ----------------
// all outputs node-major (coalesced 256B per wave)
__global__ __launch_bounds__(256) void k_hop_agg(const float* hw, const float* ssrc,
                                                 const float* sdst, const int* row_ptr,
                                                 const int* esrc, const float* gcsr,
                                                 const float* h, float* cur_nm, float* khsum_nm,
                                                 float* agg_nm, int hop) {
  int w = threadIdx.x >> 6, lane = threadIdx.x & 63;
  int node = blockIdx.x * 4 + w;
  int b = node / cN, n = node - b * cN;
  int r0 = row_ptr[n], r1 = row_ptr[n + 1];
  const float* sb = ssrc + (size_t)b * cN;
  float sd = sdst[node];
  float m = -INFINITY;
  for (int e = r0 + lane; e < r1; e += 64) {
    float ev = sb[esrc[e]] + sd;
    ev = ev > 0.f ? ev : 0.2f * ev;
    m = fmaxf(m, ev);
  }
  m = wmax(m);
  float den = 0.f, num = 0.f, lacc = 0.f;
  const float* hwb = hw + (size_t)b * cN * cH;
  const float* hb = h + (size_t)b * cN * cH;
  for (int e = r0; e < r1; e++) {
    int s = esrc[e];
    float ev = sb[s] + sd;
    ev = ev > 0.f ? ev : 0.2f * ev;
    float wgt = expf(ev - m);
    den += wgt;
    num += wgt * hwb[(size_t)s * cH + lane];
    if (hop == 0) lacc += gcsr[e] * hb[(size_t)s * cH + lane];
  }
  float cv = num / (den + 1e-16f);
  size_t ni = (size_t)node * 64 + lane;
  if (hop < 2) cur_nm[ni] = cv;
  if (hop == 0) {
    khsum_nm[ni] = cv;
    agg_nm[ni] = lacc;
  } else {
    khsum_nm[ni] += cv;
  }
}

// ---------------- p finalize: p = khsum/3 + (agg @ W_lt)/(deg+1) ----------------
__global__ __launch_bounds__(256) void k_pfin(float* z_t, const float* khsum_nm,
                                              const float* agg_nm, const int* row_ptr, fp W_lt) {
  __shared__ float tA[64 * 65];
  __shared__ float tK[64 * 65];
  int w = threadIdx.x >> 6, lane = threadIdx.x & 63;
  int base = blockIdx.x * 64, node = base + lane;
  int c0 = __builtin_amdgcn_readfirstlane(w * 16);
  {
    int tn = threadIdx.x >> 2, f0 = (threadIdx.x & 3) * 16;
    int gn = base + tn;
    if (gn >= cBN) gn = cBN - 1;
    const float4* asrc = (const float4*)(agg_nm + (size_t)gn * 64 + f0);
    const float4* ksrc = (const float4*)(khsum_nm + (size_t)gn * 64 + f0);
#pragma unroll
    for (int q = 0; q < 4; q++) {
      float4 a = asrc[q];
      float4 k = ksrc[q];
      int o = tn * 65 + f0 + q * 4;
      tA[o + 0] = a.x; tA[o + 1] = a.y; tA[o + 2] = a.z; tA[o + 3] = a.w;
      tK[o + 0] = k.x; tK[o + 1] = k.y; tK[o + 2] = k.z; tK[o + 3] = k.w;
    }
  }
  __syncthreads();
  int nd = node < cBN ? node : cBN - 1;
  int b = nd / cN, n = nd - b * cN;
  float pacc[16];
#pragma unroll
  for (int c = 0; c < 16; c++) pacc[c] = 0.f;
  for (int i = 0; i < 64; i++) {
    float av = tA[lane * 65 + i];
#pragma unroll
    for (int c = 0; c < 16; c++) pacc[c] += av * W_lt[i * 64 + c0 + c];
  }
  float idp = 1.f / ((float)(row_ptr[n + 1] - row_ptr[n]) + 1.f);
  if (node < cBN) {
#pragma unroll
    for (int c = 0; c < 16; c++) {
      z_t[(size_t)(64 + c0 + c) * cBN + node] =
          tK[lane * 65 + c0 + c] * (1.f / 3.f) + pacc[c] * idp;
    }
  }
}

// ---------------- heavy matvecs: tau/g over z(133), encoder u over phi(128) ----------------
// wave = (nodegroup, sub); sub 0..7 -> [tau|g] colchunk, sub 8..11 -> u colchunk
__global__ __launch_bounds__(256) void k_zmat(const float* z_t, fp x, int t, fp W_tau, fp b_tau,
                                              fp W_g, fp b_g, fp c_enc, fp W_enc, fp b_enc,
                                              float* tg_t, float* u_t) {
  int w = threadIdx.x >> 6, lane = threadIdx.x & 63;
  int wid = blockIdx.x * 4 + w;
  int ng = wid / 12, sub = wid - ng * 12;
  int node = ng * 64 + lane;
  int nd = node < cBN ? node : cBN - 1;
  int b = nd / cN, n = nd - b * cN;
  const float* xp = x + (((size_t)b * cT + t) * cN + n) * cF;
  float acc[16];
  if (sub < 8) {
    int c0 = __builtin_amdgcn_readfirstlane(sub * 16);  // 0..127 across [tau|g]
    const float* W = (c0 < 64) ? W_tau : W_g;
    const float* bias = (c0 < 64) ? b_tau : b_g;
    int cc = c0 & 63;
#pragma unroll
    for (int c = 0; c < 16; c++) acc[c] = bias[cc + c];
    for (int k = 0; k < 64; k++) {
      float zv = z_t[(size_t)k * cBN + nd];
#pragma unroll
      for (int c = 0; c < 16; c++) acc[c] += zv * W[k * 64 + cc + c];
    }
#pragma unroll
    for (int j = 0; j < 5; j++) {
      float zv = xp[8 + j];
      int r = 64 + j;
#pragma unroll
      for (int c = 0; c < 16; c++) acc[c] += zv * W[r * 64 + cc + c];
    }
    for (int k = 0; k < 64; k++) {
      float zv = z_t[(size_t)(64 + k) * cBN + nd];
      int r = 69 + k;
#pragma unroll
      for (int c = 0; c < 16; c++) acc[c] += zv * W[r * 64 + cc + c];
    }
    if (node < cBN) {
#pragma unroll
      for (int c = 0; c < 16; c++) tg_t[(size_t)(c0 + c) * cBN + node] = acc[c];
    }
  } else {
    int cu = __builtin_amdgcn_readfirstlane((sub - 8) * 16);
    float ec0 = c_enc[0], ec7 = c_enc[7];
    float inv_e = 7.f / (ec7 - ec0);
#pragma unroll
    for (int c = 0; c < 16; c++) acc[c] = b_enc[cu + c];
    for (int f = 0; f < 16; f++) {
      float xv = xp[f];
#pragma unroll
      for (int cb = 0; cb < 8; cb++) {
        float d = (xv - c_enc[cb]) * inv_e;
        float ph = __expf(-d * d);
        const float* Wr = W_enc + (f * 8 + cb) * 64 + cu;
#pragma unroll
        for (int c = 0; c < 16; c++) acc[c] += ph * Wr[c];
      }
    }
    if (node < cBN) {
#pragma unroll
      for (int c = 0; c < 16; c++) u_t[(size_t)(cu + c) * cBN + node] = acc[c];
    }
  }
}

// ---------------- light cell: liquid + LN + u + decoder + h transpose ----------------
__global__ __launch_bounds__(256) void k_cell2(float* z_t, float* h, const float* tg_t,
                                               const float* u_t, fp gamma, fp beta, fp cdec,
                                               fp W_dec, fp b_dec, int t, float* out) {
  __shared__ float tile[64 * 65];
  __shared__ float redm[4][64], redv[4][64];
  __shared__ float redp[4][3][64];
  int w = threadIdx.x >> 6, lane = threadIdx.x & 63;
  int base = blockIdx.x * 64, node = base + lane;
  int nd = node < cBN ? node : cBN - 1;
  int b = nd / cN, n = nd - b * cN;
  int c0 = __builtin_amdgcn_readfirstlane(w * 16);
  float acc[16];
  float pm = 0.f;
#pragma unroll
  for (int c = 0; c < 16; c++) {
    float hcur = z_t[(size_t)(c0 + c) * cBN + nd];
    float at = tg_t[(size_t)(c0 + c) * cBN + nd];
    float ag = tg_t[(size_t)(64 + c0 + c) * cBN + nd];
    float tau = 1.f + 9.f / (1.f + __expf(-at));
    float g = tanhf(ag);
    float v = hcur + 0.25f * (g - hcur) / tau;
    acc[c] = v;
    pm += v;
  }
  redm[w][lane] = pm;
  __syncthreads();
  float mu = (redm[0][lane] + redm[1][lane] + redm[2][lane] + redm[3][lane]) * (1.f / 64.f);
  float pv = 0.f;
#pragma unroll
  for (int c = 0; c < 16; c++) {
    float d = acc[c] - mu;
    pv += d * d;
  }
  redv[w][lane] = pv;
  __syncthreads();
  float var = (redv[0][lane] + redv[1][lane] + redv[2][lane] + redv[3][lane]) * (1.f / 64.f);
  float rstd = rsqrtf(var + 1e-5f);
#pragma unroll
  for (int c = 0; c < 16; c++) {
    acc[c] = (acc[c] - mu) * rstd * gamma[c0 + c] + beta[c0 + c] +
             u_t[(size_t)(c0 + c) * cBN + nd];
  }
  // store h (col-major for zmat) + stage node-major transpose
  if (node < cBN) {
#pragma unroll
    for (int c = 0; c < 16; c++) z_t[(size_t)(c0 + c) * cBN + node] = acc[c];
  }
#pragma unroll
  for (int c = 0; c < 16; c++) tile[(c0 + c) * 65 + lane] = acc[c];
  // decoder fastkan + softplus
  float dc0 = cdec[0], dc7 = cdec[7];
  float inv_d = 7.f / (dc7 - dc0);
  float p0 = 0.f, p1 = 0.f, p2 = 0.f;
#pragma unroll
  for (int c = 0; c < 16; c++) {
#pragma unroll
    for (int j = 0; j < 8; j++) {
      float dd = (acc[c] - cdec[j]) * inv_d;
      float ph = __expf(-dd * dd);
      int bb = ((c0 + c) * 8 + j) * 3;
      p0 += ph * W_dec[bb];
      p1 += ph * W_dec[bb + 1];
      p2 += ph * W_dec[bb + 2];
    }
  }
  redp[w][0][lane] = p0;
  redp[w][1][lane] = p1;
  redp[w][2][lane] = p2;
  __syncthreads();
  for (int r = w; r < 64; r += 4) {
    if (base + r < cBN) h[(size_t)(base + r) * 64 + lane] = tile[lane * 65 + r];
  }
  if (w == 0 && node < cBN) {
    float v0 = redp[0][0][lane] + redp[1][0][lane] + redp[2][0][lane] + redp[3][0][lane] + b_dec[0];
    float v1 = redp[0][1][lane] + redp[1][1][lane] + redp[2][1][lane] + redp[3][1][lane] + b_dec[1];
    float v2 = redp[0][2][lane] + redp[1][2][lane] + redp[2][2][lane] + redp[3][2][lane] + b_dec[2];
    size_t ob = (((size_t)b * cT + t) * cN + n) * 3;
    out[ob] = fmaxf(v0, 0.f) + log1pf(expf(-fabsf(v0)));
    out[ob + 1] = fmaxf(v1, 0.f) + log1pf(expf(-fabsf(v1)));
    out[ob + 2] = fmaxf(v2, 0.f) + log1pf(expf(-fabsf(v2)));
  }
}

extern "C" void kernel_launch(void* const* d_in, const int* in_sizes, int n_in, void* d_out,
                              int out_size, void* d_ws, size_t ws_size, hipStream_t stream) {
  fp x = (fp)d_in[0];
  fp edge_attr = (fp)d_in[1];
  fp c_enc = (fp)d_in[2];
  fp W_enc = (fp)d_in[3];
  fp b_enc = (fp)d_in[4];
  fp W_hop = (fp)d_in[5];
  fp a_src = (fp)d_in[6];
  fp a_dst = (fp)d_in[7];
  fp w_lt1 = (fp)d_in[8];
  fp b_lt1 = (fp)d_in[9];
  fp w_lt2 = (fp)d_in[10];
  fp b_lt2 = (fp)d_in[11];
  fp W_lt = (fp)d_in[12];
  fp W_tau = (fp)d_in[13];
  fp b_tau = (fp)d_in[14];
  fp W_g = (fp)d_in[15];
  fp b_g = (fp)d_in[16];
  fp gamma = (fp)d_in[17];
  fp beta = (fp)d_in[18];
  fp c_dec = (fp)d_in[19];
  fp W_dec = (fp)d_in[20];
  fp b_dec = (fp)d_in[21];
  fp h0 = (fp)d_in[22];
  const int* eidx = (const int*)d_in[23];
  const int* esrc_in = eidx;
  const int* edst_in = eidx + cE;

  float* fws = (float*)d_ws;
  float* z_t = fws;      fws += 128 * cBN;  // rows 0..63 h_t, 64..127 p
  float* cur_nm = fws;   fws += 64 * cBN;   // node-major; aliased as u_t after hops
  float* khsum_nm = fws; fws += 64 * cBN;   // node-major
  float* hw = fws;       fws += cBNH;       // node-major
  float* h = fws;        fws += cBNH;       // node-major
  float* agg_nm = fws;   fws += 64 * cBN;   // node-major
  float* tg_t = fws;     fws += 128 * cBN;  // col-major
  float* ssrc = fws;     fws += cBN;
  float* sdst = fws;     fws += cBN;
  float* gcsr = fws;     fws += cE;
  int* iws = (int*)fws;
  int* esrc = iws;       iws += cE;
  int* row_ptr = iws;    iws += cN + 1;
  int* cursor = iws;     iws += cN;
  int* counts = iws;     iws += cN;
  float* u_t = cur_nm;  // cur_nm dead after hop-2 matvec; u_t live zmat->cell2

  k_zero_i32<<<(cN + 255) / 256, 256, 0, stream>>>(counts, cN);
  k_count<<<(cE + 255) / 256, 256, 0, stream>>>(edst_in, counts);
  k_scan<<<1, 1024, 0, stream>>>(counts, row_ptr, cursor);
  k_scatter<<<(cE + 255) / 256, 256, 0, stream>>>(esrc_in, edst_in, edge_attr, w_lt1, b_lt1,
                                                  w_lt2, b_lt2, cursor, esrc, gcsr);
  k_init<<<(cBNH + 255) / 256, 256, 0, stream>>>(h, z_t, h0);

  for (int t = 0; t < cT; t++) {
    for (int k = 0; k < cK; k++) {
      k_hop_mat_t<<<NBLK, 256, 0, stream>>>(k == 0 ? h : cur_nm, W_hop + (size_t)k * cH * cH,
                                            a_src + k * cH, a_dst + k * cH, hw, ssrc, sdst);
      k_hop_agg<<<cBN / 4, 256, 0, stream>>>(hw, ssrc, sdst, row_ptr, esrc, gcsr, h, cur_nm,
                                             khsum_nm, agg_nm, k);
    }
    k_pfin<<<NBLK, 256, 0, stream>>>(z_t, khsum_nm, agg_nm, row_ptr, W_lt);
    k_zmat<<<(NBLK * 12 + 3) / 4, 256, 0, stream>>>(z_t, x, t, W_tau, b_tau, W_g, b_g, c_enc,
                                                    W_enc, b_enc, tg_t, u_t);
    k_cell2<<<NBLK, 256, 0, stream>>>(z_t, h, tg_t, u_t, gamma, beta, c_dec, W_dec, b_dec, t,
                                      (float*)d_out);
  }
}

// Round 7
// 1133.408 us; speedup vs baseline: 1.2757x; 1.0140x over previous
//
#include <hip/hip_runtime.h>
#include <math.h>

// SeaLiceGLKAN — fp32 in/out. Per-step dense chain fused into one
// block-per-nodegroup kernel (z vector staged in LDS, weights via wave-uniform
// scalar loads). Edge gathers lane=H with node-major coalesced outputs.

constexpr int cB = 2, cT = 4, cN = 10000, cF = 16, cH = 64, cE = 160000, cNB = 8, cK = 3;
constexpr int cBN = cB * cN;    // 20000
constexpr int cBNH = cBN * cH;  // 1,280,000
constexpr int NBLK = (cBN + 63) / 64;  // 313 nodegroups of 64 nodes

typedef const float* fp;

__device__ __forceinline__ float wmax(float v) {
#pragma unroll
  for (int o = 1; o < 64; o <<= 1) v = fmaxf(v, __shfl_xor(v, o, 64));
  return v;
}

// ---------------- CSR build ----------------
__global__ void k_zero_i32(int* p, int n) {
  int i = blockIdx.x * 256 + threadIdx.x;
  if (i < n) p[i] = 0;
}

__global__ void k_count(const int* dst, int* counts) {
  int e = blockIdx.x * 256 + threadIdx.x;
  if (e < cE) atomicAdd(&counts[dst[e]], 1);
}

__global__ void k_scan(const int* counts, int* row_ptr, int* cursor) {
  __shared__ int part[1024];
  int t = threadIdx.x;
  const int CH = (cN + 1023) / 1024;  // 10
  int s = 0;
  for (int i = 0; i < CH; i++) {
    int idx = t * CH + i;
    if (idx < cN) s += counts[idx];
  }
  part[t] = s;
  __syncthreads();
  for (int off = 1; off < 1024; off <<= 1) {
    int v = (t >= off) ? part[t - off] : 0;
    __syncthreads();
    part[t] += v;
    __syncthreads();
  }
  int excl = (t == 0) ? 0 : part[t - 1];
  for (int i = 0; i < CH; i++) {
    int idx = t * CH + i;
    if (idx < cN) {
      row_ptr[idx] = excl;
      cursor[idx] = excl;
      excl += counts[idx];
    }
  }
  if (t == 1023) row_ptr[cN] = part[1023];
}

__global__ void k_scatter(const int* src, const int* dst, fp ea, fp w1, fp b1, fp w2, fp b2,
                          int* cursor, int* esrc, float* gcsr) {
  int e = blockIdx.x * 256 + threadIdx.x;
  if (e >= cE) return;
  float a0 = ea[e * 4 + 0], a1 = ea[e * 4 + 1], a2 = ea[e * 4 + 2], a3 = ea[e * 4 + 3];
  float acc = b2[0];
#pragma unroll
  for (int j = 0; j < 16; j++) {
    float tv = b1[j] + a0 * w1[j] + a1 * w1[16 + j] + a2 * w1[32 + j] + a3 * w1[48 + j];
    acc += tanhf(tv) * w2[j];
  }
  float g = 1.f / (1.f + expf(-acc));
  int p = atomicAdd(&cursor[dst[e]], 1);
  esrc[p] = src[e];
  gcsr[p] = g;
}

__global__ void k_init(float* h, fp h0) {
  int i = blockIdx.x * 256 + threadIdx.x;
  if (i < cBNH) h[i] = h0[i & 63];
}

// ---------------- hop matvec: node-major input via LDS, lane=node ----------------
__global__ __launch_bounds__(256) void k_hop_mat_t(const float* vin_nm, fp Wh, fp avs, fp avd,
                                                   float* hw, float* ssrc, float* sdst) {
  __shared__ float tin[64 * 65];
  __shared__ float tout[64 * 65];
  __shared__ float red1[4][64], red2[4][64];
  int w = threadIdx.x >> 6, lane = threadIdx.x & 63;
  int base = blockIdx.x * 64, node = base + lane;
  int c0 = __builtin_amdgcn_readfirstlane(w * 16);
  {
    int tn = threadIdx.x >> 2, f0 = (threadIdx.x & 3) * 16;
    int gn = base + tn;
    if (gn >= cBN) gn = cBN - 1;
    const float4* vsrc = (const float4*)(vin_nm + (size_t)gn * 64 + f0);
#pragma unroll
    for (int q = 0; q < 4; q++) {
      float4 v = vsrc[q];
      int o = tn * 65 + f0 + q * 4;
      tin[o + 0] = v.x; tin[o + 1] = v.y; tin[o + 2] = v.z; tin[o + 3] = v.w;
    }
  }
  __syncthreads();
  float acc[16];
#pragma unroll
  for (int c = 0; c < 16; c++) acc[c] = 0.f;
  for (int i = 0; i < 64; i++) {
    float cv = tin[lane * 65 + i];
#pragma unroll
    for (int c = 0; c < 16; c++) acc[c] += cv * Wh[i * 64 + c0 + c];
  }
  float r1 = 0.f, r2 = 0.f;
#pragma unroll
  for (int c = 0; c < 16; c++) {
    r1 += acc[c] * avs[c0 + c];
    r2 += acc[c] * avd[c0 + c];
  }
  red1[w][lane] = r1;
  red2[w][lane] = r2;
#pragma unroll
  for (int c = 0; c < 16; c++) tout[(c0 + c) * 65 + lane] = acc[c];
  __syncthreads();
  if (w == 0 && node < cBN) {
    ssrc[node] = red1[0][lane] + red1[1][lane] + red1[2][lane] + red1[3][lane];
    sdst[node] = red2[0][lane] + red2[1][lane] + red2[2][lane] + red2[3][lane];
  }
  for (int r = w; r < 64; r += 4) {
    if (base + r < cBN) hw[(size_t)(base + r) * 64 + lane] = tout[lane * 65 + r];
  }
}

// ---------------- hop aggregate (lane=H) + larval fused at hop 0 ----------------
__global__ __launch_bounds__(256) void k_hop_agg(const float* hw, const float* ssrc,
                                                 const float* sdst, const int* row_ptr,
                                                 const int* esrc, const float* gcsr,
                                                 const float* h, float* cur_nm, float* khsum_nm,
                                                 float* agg_nm, int hop) {
  int w = threadIdx.x >> 6, lane = threadIdx.x & 63;
  int node = blockIdx.x * 4 + w;
  int b = node / cN, n = node - b * cN;
  int r0 = row_ptr[n], r1 = row_ptr[n + 1];
  const float* sb = ssrc + (size_t)b * cN;
  float sd = sdst[node];
  float m = -INFINITY;
  for (int e = r0 + lane; e < r1; e += 64) {
    float ev = sb[esrc[e]] + sd;
    ev = ev > 0.f ? ev : 0.2f * ev;
    m = fmaxf(m, ev);
  }
  m = wmax(m);
  float den = 0.f, num = 0.f, lacc = 0.f;
  const float* hwb = hw + (size_t)b * cN * cH;
  const float* hb = h + (size_t)b * cN * cH;
  for (int e = r0; e < r1; e++) {
    int s = esrc[e];
    float ev = sb[s] + sd;
    ev = ev > 0.f ? ev : 0.2f * ev;
    float wgt = expf(ev - m);
    den += wgt;
    num += wgt * hwb[(size_t)s * cH + lane];
    if (hop == 0) lacc += gcsr[e] * hb[(size_t)s * cH + lane];
  }
  float cv = num / (den + 1e-16f);
  size_t ni = (size_t)node * 64 + lane;
  if (hop < 2) cur_nm[ni] = cv;
  if (hop == 0) {
    khsum_nm[ni] = cv;
    agg_nm[ni] = lacc;
  } else {
    khsum_nm[ni] += cv;
  }
}

// ---------------- fused dense step: p-finalize + tau/g/u matvecs + cell + decoder ----
__global__ __launch_bounds__(256) void k_cell_f(fp x, int t, float* h, const float* khsum_nm,
                                                const float* agg_nm, const int* row_ptr,
                                                fp W_lt, fp W_tau, fp b_tau, fp W_g, fp b_g,
                                                fp gamma, fp beta, fp c_enc, fp W_enc, fp b_enc,
                                                fp cdec, fp W_dec, fp b_dec, float* out) {
  __shared__ float tin[133 * 65];  // [z-row][node]; rows 0..63 h, 64..68 env, 69..132 p
  __shared__ float tAgg[64 * 65];  // [node][i] agg; reused as transpose tile later
  __shared__ float sx[64 * 17];    // [node][f]
  __shared__ float redm[4][64], redv[4][64];
  __shared__ float redp[4][3][64];
  int w = threadIdx.x >> 6, lane = threadIdx.x & 63;
  int base = blockIdx.x * 64, node = base + lane;
  int nd = node < cBN ? node : cBN - 1;
  int bb = nd / cN, nn = nd - bb * cN;
  int c0 = __builtin_amdgcn_readfirstlane(w * 16);
  // ---- staging (coalesced) ----
  {
    int tn = threadIdx.x >> 2;
    int gn = base + tn;
    if (gn >= cBN) gn = cBN - 1;
    int gb = gn / cN, gnn = gn - gb * cN;
    int f4 = (threadIdx.x & 3) * 4;
    float4 xv4 = *(const float4*)(x + (((size_t)gb * cT + t) * cN + gnn) * cF + f4);
    sx[tn * 17 + f4 + 0] = xv4.x;
    sx[tn * 17 + f4 + 1] = xv4.y;
    sx[tn * 17 + f4 + 2] = xv4.z;
    sx[tn * 17 + f4 + 3] = xv4.w;
    int f0 = (threadIdx.x & 3) * 16;
    const float4* hsrc = (const float4*)(h + (size_t)gn * 64 + f0);
    const float4* ksrc = (const float4*)(khsum_nm + (size_t)gn * 64 + f0);
    const float4* asrc = (const float4*)(agg_nm + (size_t)gn * 64 + f0);
#pragma unroll
    for (int q = 0; q < 4; q++) {
      float4 hv = hsrc[q];
      float4 kv = ksrc[q];
      float4 av = asrc[q];
      int f = f0 + q * 4;
      tin[(f + 0) * 65 + tn] = hv.x; tin[(f + 1) * 65 + tn] = hv.y;
      tin[(f + 2) * 65 + tn] = hv.z; tin[(f + 3) * 65 + tn] = hv.w;
      tin[(69 + f + 0) * 65 + tn] = kv.x * (1.f / 3.f);
      tin[(69 + f + 1) * 65 + tn] = kv.y * (1.f / 3.f);
      tin[(69 + f + 2) * 65 + tn] = kv.z * (1.f / 3.f);
      tin[(69 + f + 3) * 65 + tn] = kv.w * (1.f / 3.f);
      tAgg[tn * 65 + f + 0] = av.x; tAgg[tn * 65 + f + 1] = av.y;
      tAgg[tn * 65 + f + 2] = av.z; tAgg[tn * 65 + f + 3] = av.w;
    }
  }
  __syncthreads();
  // env rows 64..68 (read sx post-sync)
  for (int i = threadIdx.x; i < 320; i += 256) {
    int j = i >> 6, n2 = i & 63;
    tin[(64 + j) * 65 + n2] = sx[n2 * 17 + 8 + j];
  }
  // ---- phase 1: p = khsum/3 + (agg @ W_lt)/(deg+1) ----
  {
    float pacc[16];
#pragma unroll
    for (int c = 0; c < 16; c++) pacc[c] = 0.f;
    for (int i = 0; i < 64; i++) {
      float av = tAgg[lane * 65 + i];
#pragma unroll
      for (int c = 0; c < 16; c++) pacc[c] += av * W_lt[i * 64 + c0 + c];
    }
    float idp = 1.f / ((float)(row_ptr[nn + 1] - row_ptr[nn]) + 1.f);
#pragma unroll
    for (int c = 0; c < 16; c++) {
      int r = (69 + c0 + c) * 65 + lane;
      tin[r] = tin[r] + pacc[c] * idp;
    }
  }
  __syncthreads();
  // ---- phase 2: tau/g matvec over z(133) from LDS, weights scalar ----
  float accT[16], accG[16];
#pragma unroll
  for (int c = 0; c < 16; c++) {
    accT[c] = b_tau[c0 + c];
    accG[c] = b_g[c0 + c];
  }
  for (int k = 0; k < 133; k++) {
    float zv = tin[k * 65 + lane];
#pragma unroll
    for (int c = 0; c < 16; c++) {
      accT[c] += zv * W_tau[k * 64 + c0 + c];
      accG[c] += zv * W_g[k * 64 + c0 + c];
    }
  }
  // ---- encoder u ----
  float accU[16];
#pragma unroll
  for (int c = 0; c < 16; c++) accU[c] = b_enc[c0 + c];
  {
    float ec0 = c_enc[0], ec7 = c_enc[7];
    float inv_e = 7.f / (ec7 - ec0);
    for (int f = 0; f < 16; f++) {
      float xvf = sx[lane * 17 + f];
#pragma unroll
      for (int cb = 0; cb < 8; cb++) {
        float d = (xvf - c_enc[cb]) * inv_e;
        float ph = __expf(-d * d);
        const float* Wr = W_enc + (f * 8 + cb) * 64 + c0;
#pragma unroll
        for (int c = 0; c < 16; c++) accU[c] += ph * Wr[c];
      }
    }
  }
  // ---- liquid + LayerNorm ----
  float pm = 0.f;
#pragma unroll
  for (int c = 0; c < 16; c++) {
    float hcur = tin[(c0 + c) * 65 + lane];
    float tau = 1.f + 9.f / (1.f + __expf(-accT[c]));
    float g = tanhf(accG[c]);
    float v = hcur + 0.25f * (g - hcur) / tau;
    accT[c] = v;
    pm += v;
  }
  redm[w][lane] = pm;
  __syncthreads();
  float mu = (redm[0][lane] + redm[1][lane] + redm[2][lane] + redm[3][lane]) * (1.f / 64.f);
  float pv = 0.f;
#pragma unroll
  for (int c = 0; c < 16; c++) {
    float d = accT[c] - mu;
    pv += d * d;
  }
  redv[w][lane] = pv;
  __syncthreads();
  float var = (redv[0][lane] + redv[1][lane] + redv[2][lane] + redv[3][lane]) * (1.f / 64.f);
  float rstd = rsqrtf(var + 1e-5f);
#pragma unroll
  for (int c = 0; c < 16; c++)
    accT[c] = (accT[c] - mu) * rstd * gamma[c0 + c] + beta[c0 + c] + accU[c];
  // ---- h write (transpose via reused tAgg tile) + decoder ----
  float* tile = tAgg;
#pragma unroll
  for (int c = 0; c < 16; c++) tile[(c0 + c) * 65 + lane] = accT[c];
  float dc0 = cdec[0], dc7 = cdec[7];
  float inv_d = 7.f / (dc7 - dc0);
  float p0 = 0.f, p1 = 0.f, p2 = 0.f;
#pragma unroll
  for (int c = 0; c < 16; c++) {
#pragma unroll
    for (int j = 0; j < 8; j++) {
      float dd = (accT[c] - cdec[j]) * inv_d;
      float ph = __expf(-dd * dd);
      int bb2 = ((c0 + c) * 8 + j) * 3;
      p0 += ph * W_dec[bb2];
      p1 += ph * W_dec[bb2 + 1];
      p2 += ph * W_dec[bb2 + 2];
    }
  }
  redp[w][0][lane] = p0;
  redp[w][1][lane] = p1;
  redp[w][2][lane] = p2;
  __syncthreads();
  for (int r = w; r < 64; r += 4) {
    if (base + r < cBN) h[(size_t)(base + r) * 64 + lane] = tile[lane * 65 + r];
  }
  if (w == 0 && node < cBN) {
    float v0 = redp[0][0][lane] + redp[1][0][lane] + redp[2][0][lane] + redp[3][0][lane] + b_dec[0];
    float v1 = redp[0][1][lane] + redp[1][1][lane] + redp[2][1][lane] + redp[3][1][lane] + b_dec[1];
    float v2 = redp[0][2][lane] + redp[1][2][lane] + redp[2][2][lane] + redp[3][2][lane] + b_dec[2];
    size_t ob = (((size_t)bb * cT + t) * cN + nn) * 3;
    out[ob] = fmaxf(v0, 0.f) + log1pf(expf(-fabsf(v0)));
    out[ob + 1] = fmaxf(v1, 0.f) + log1pf(expf(-fabsf(v1)));
    out[ob + 2] = fmaxf(v2, 0.f) + log1pf(expf(-fabsf(v2)));
  }
}

extern "C" void kernel_launch(void* const* d_in, const int* in_sizes, int n_in, void* d_out,
                              int out_size, void* d_ws, size_t ws_size, hipStream_t stream) {
  fp x = (fp)d_in[0];
  fp edge_attr = (fp)d_in[1];
  fp c_enc = (fp)d_in[2];
  fp W_enc = (fp)d_in[3];
  fp b_enc = (fp)d_in[4];
  fp W_hop = (fp)d_in[5];
  fp a_src = (fp)d_in[6];
  fp a_dst = (fp)d_in[7];
  fp w_lt1 = (fp)d_in[8];
  fp b_lt1 = (fp)d_in[9];
  fp w_lt2 = (fp)d_in[10];
  fp b_lt2 = (fp)d_in[11];
  fp W_lt = (fp)d_in[12];
  fp W_tau = (fp)d_in[13];
  fp b_tau = (fp)d_in[14];
  fp W_g = (fp)d_in[15];
  fp b_g = (fp)d_in[16];
  fp gamma = (fp)d_in[17];
  fp beta = (fp)d_in[18];
  fp c_dec = (fp)d_in[19];
  fp W_dec = (fp)d_in[20];
  fp b_dec = (fp)d_in[21];
  fp h0 = (fp)d_in[22];
  const int* eidx = (const int*)d_in[23];
  const int* esrc_in = eidx;
  const int* edst_in = eidx + cE;

  float* fws = (float*)d_ws;
  float* h = fws;        fws += cBNH;      // node-major
  float* cur_nm = fws;   fws += cBNH;      // node-major
  float* khsum_nm = fws; fws += cBNH;      // node-major
  float* agg_nm = fws;   fws += cBNH;      // node-major
  float* hw = fws;       fws += cBNH;      // node-major
  float* ssrc = fws;     fws += cBN;
  float* sdst = fws;     fws += cBN;
  float* gcsr = fws;     fws += cE;
  int* iws = (int*)fws;
  int* esrc = iws;       iws += cE;
  int* row_ptr = iws;    iws += cN + 1;
  int* cursor = iws;     iws += cN;
  int* counts = iws;     iws += cN;

  k_zero_i32<<<(cN + 255) / 256, 256, 0, stream>>>(counts, cN);
  k_count<<<(cE + 255) / 256, 256, 0, stream>>>(edst_in, counts);
  k_scan<<<1, 1024, 0, stream>>>(counts, row_ptr, cursor);
  k_scatter<<<(cE + 255) / 256, 256, 0, stream>>>(esrc_in, edst_in, edge_attr, w_lt1, b_lt1,
                                                  w_lt2, b_lt2, cursor, esrc, gcsr);
  k_init<<<(cBNH + 255) / 256, 256, 0, stream>>>(h, h0);

  for (int t = 0; t < cT; t++) {
    for (int k = 0; k < cK; k++) {
      k_hop_mat_t<<<NBLK, 256, 0, stream>>>(k == 0 ? h : cur_nm, W_hop + (size_t)k * cH * cH,
                                            a_src + k * cH, a_dst + k * cH, hw, ssrc, sdst);
      k_hop_agg<<<cBN / 4, 256, 0, stream>>>(hw, ssrc, sdst, row_ptr, esrc, gcsr, h, cur_nm,
                                             khsum_nm, agg_nm, k);
    }
    k_cell_f<<<NBLK, 256, 0, stream>>>(x, t, h, khsum_nm, agg_nm, row_ptr, W_lt, W_tau, b_tau,
                                       W_g, b_g, gamma, beta, c_enc, W_enc, b_enc, c_dec, W_dec,
                                       b_dec, (float*)d_out);
  }
}